// Round 1
// baseline (2755.836 us; speedup 1.0000x reference)
//
#include <hip/hip_runtime.h>
#include <float.h>

#define NROWS 32768   // B*S = 8*4096
#define KDIM  512
#define NEMB  4096

#define TM 128
#define TN 128
#define TK 16
#define XS_STRIDE 132   // pad to break bank conflicts on transposed writes

#define NCB (NEMB / TN)  // 32 code blocks

// ---- ws layout (float units) ----
#define OFF_NORMS 0u
#define OFF_ET    4096u
#define OFF_PART  (OFF_ET + (unsigned)(NEMB * KDIM))          // float2 pairs: NROWS*NCB
#define OFF_IDX   (OFF_PART + (unsigned)(NROWS * NCB * 2))
#define OFF_DP    (OFF_IDX + (unsigned)NROWS)
#define WS_FLOATS (OFF_DP + 2048u)

// ---- out layout (float units) ----
#define OUT_Q    0u
#define OUT_DIFF 16777216u
#define OUT_IDX  16777217u

// ---------------- kernel 1: code norms ||e_j||^2 ----------------
__global__ __launch_bounds__(256) void k_norms(const float* __restrict__ e,
                                               float* __restrict__ norms) {
    int j = blockIdx.x * 256 + threadIdx.x;   // 4096 threads, coalesced over j
    float s = 0.f;
    for (int k = 0; k < KDIM; ++k) {
        float v = e[(size_t)k * NEMB + j];
        s += v * v;
    }
    norms[j] = s;
}

// ---------------- kernel 2: transpose embed -> embedT[4096][512] ----------------
__global__ __launch_bounds__(256) void k_transpose(const float* __restrict__ e,
                                                   float* __restrict__ et) {
    __shared__ float t[32][33];
    int jb = blockIdx.x * 32;   // code dim
    int kb = blockIdx.y * 32;   // feature dim
    int tx = threadIdx.x;       // 32
    int ty = threadIdx.y;       // 8
    for (int i = ty; i < 32; i += 8)
        t[i][tx] = e[(size_t)(kb + i) * NEMB + jb + tx];
    __syncthreads();
    for (int i = ty; i < 32; i += 8)
        et[(size_t)(jb + i) * KDIM + kb + tx] = t[tx][i];
}

// ---------------- kernel 3: tiled fp32 GEMM + per-code-block argmin ----------------
__global__ __launch_bounds__(256) void k_gemm_argmin(
        const float* __restrict__ x,      // [NROWS][KDIM]
        const float* __restrict__ e,      // [KDIM][NEMB]
        const float* __restrict__ norms,  // [NEMB]
        float2* __restrict__ part)        // [NROWS][NCB] (score, idx-bits)
{
    __shared__ float xs[TK][XS_STRIDE];     // A tile, transposed [k][row]
    __shared__ float es[TK][TN];            // B tile [k][col]
    __shared__ float2 red[TM][16];          // argmin reduction buffer

    const int rb = blockIdx.x;          // 0..255
    const int cb = blockIdx.y;          // 0..31
    const int row0 = rb * TM;
    const int col0 = cb * TN;
    const int tid = threadIdx.x;
    const int ty = tid >> 4;            // 0..15 : row group
    const int tx = tid & 15;            // 0..15 : col group

    float acc[8][8];
#pragma unroll
    for (int i = 0; i < 8; ++i)
#pragma unroll
        for (int j = 0; j < 8; ++j) acc[i][j] = 0.f;

    for (int k0 = 0; k0 < KDIM; k0 += TK) {
        __syncthreads();   // protect previous tile's consumers
        // stage X tile: 128 rows x 16 k (512 float4 slots, 2 per thread)
#pragma unroll
        for (int s = 0; s < 2; ++s) {
            int slot = tid + s * 256;
            int r  = slot >> 2;
            int c4 = slot & 3;
            float4 v = *(const float4*)(x + (size_t)(row0 + r) * KDIM + k0 + c4 * 4);
            xs[c4 * 4 + 0][r] = v.x;
            xs[c4 * 4 + 1][r] = v.y;
            xs[c4 * 4 + 2][r] = v.z;
            xs[c4 * 4 + 3][r] = v.w;
        }
        // stage E tile: 16 k x 128 cols (512 float4 slots)
#pragma unroll
        for (int s = 0; s < 2; ++s) {
            int slot = tid + s * 256;
            int k  = slot >> 5;
            int c4 = slot & 31;
            *(float4*)(&es[k][c4 * 4]) =
                *(const float4*)(e + (size_t)(k0 + k) * NEMB + col0 + c4 * 4);
        }
        __syncthreads();

#pragma unroll
        for (int k = 0; k < TK; ++k) {
            float xv[8], ev[8];
            *(float4*)&xv[0] = *(const float4*)&xs[k][ty * 8];
            *(float4*)&xv[4] = *(const float4*)&xs[k][ty * 8 + 4];
            *(float4*)&ev[0] = *(const float4*)&es[k][tx * 8];
            *(float4*)&ev[4] = *(const float4*)&es[k][tx * 8 + 4];
#pragma unroll
            for (int i = 0; i < 8; ++i)
#pragma unroll
                for (int j = 0; j < 8; ++j)
                    acc[i][j] += xv[i] * ev[j];
        }
    }

    // epilogue: scores = norms[j] - 2*dot ; per-thread argmin over its 8 cols
    float nrm[8];
#pragma unroll
    for (int j = 0; j < 8; ++j) nrm[j] = norms[col0 + tx * 8 + j];

#pragma unroll
    for (int i = 0; i < 8; ++i) {
        float best = FLT_MAX;
        int bj = 0;
        #pragma unroll
        for (int j = 0; j < 8; ++j) {
            float sc = nrm[j] - 2.f * acc[i][j];
            if (sc < best) { best = sc; bj = tx * 8 + j; }   // strict <: first index wins
        }
        red[ty * 8 + i][tx] = make_float2(best, __int_as_float(bj));
    }
    __syncthreads();

    if (tid < TM) {
        float best = FLT_MAX;
        int bj = 0;
        for (int t = 0; t < 16; ++t) {          // ascending tx = ascending code index
            float2 p = red[tid][t];
            if (p.x < best) { best = p.x; bj = __float_as_int(p.y); }
        }
        part[(size_t)(row0 + tid) * NCB + cb] =
            make_float2(best, __int_as_float(col0 + bj));
    }
}

// ---------------- kernel 4: reduce partial argmins, emit final index ----------------
__global__ __launch_bounds__(256) void k_reduce(const float2* __restrict__ part,
                                                int* __restrict__ idx_out,
                                                float* __restrict__ out) {
    int row = blockIdx.x * 256 + threadIdx.x;
    float best = FLT_MAX;
    int bj = 0;
    for (int cbi = 0; cbi < NCB; ++cbi) {       // ascending = ascending code index
        float2 p = part[(size_t)row * NCB + cbi];
        if (p.x < best) { best = p.x; bj = __float_as_int(p.y); }
    }
    idx_out[row] = bj;
    out[OUT_IDX + row] = (float)bj;
}

// ---------------- kernel 5: gather quantize + diff partial sums ----------------
__global__ __launch_bounds__(256) void k_gather(const float* __restrict__ x,
                                                const float* __restrict__ et,
                                                const int* __restrict__ idx,
                                                float* __restrict__ out,
                                                float* __restrict__ dpart) {
    const int b = blockIdx.x;          // 2048 blocks x 16 rows
    const int tid = threadIdx.x;
    const int row0 = b * 16;
    float s = 0.f;
    for (int i = tid; i < 16 * KDIM; i += 256) {
        int r = i >> 9;
        int k = i & (KDIM - 1);
        int row = row0 + r;
        float q  = et[(size_t)idx[row] * KDIM + k];
        float xv = x[(size_t)row * KDIM + k];
        float d = q - xv;
        s += d * d;
        out[OUT_Q + (size_t)row * KDIM + k] = q;
    }
    // wave reduce (64 lanes)
#pragma unroll
    for (int off = 32; off >= 1; off >>= 1) s += __shfl_down(s, off, 64);
    __shared__ float ws_[4];
    int lane = tid & 63, wv = tid >> 6;
    if (lane == 0) ws_[wv] = s;
    __syncthreads();
    if (tid == 0) dpart[b] = ws_[0] + ws_[1] + ws_[2] + ws_[3];
}

// ---------------- kernel 6: final diff ----------------
__global__ __launch_bounds__(256) void k_diff(const float* __restrict__ dpart,
                                              float* __restrict__ out) {
    int tid = threadIdx.x;
    float s = 0.f;
    for (int i = tid; i < 2048; i += 256) s += dpart[i];
#pragma unroll
    for (int off = 32; off >= 1; off >>= 1) s += __shfl_down(s, off, 64);
    __shared__ float ws_[4];
    int lane = tid & 63, wv = tid >> 6;
    if (lane == 0) ws_[wv] = s;
    __syncthreads();
    if (tid == 0) out[OUT_DIFF] = (ws_[0] + ws_[1] + ws_[2] + ws_[3]) / 16777216.f;
}

extern "C" void kernel_launch(void* const* d_in, const int* in_sizes, int n_in,
                              void* d_out, int out_size, void* d_ws, size_t ws_size,
                              hipStream_t stream) {
    const float* x = (const float*)d_in[0];   // [8,4096,512]
    const float* e = (const float*)d_in[1];   // [512,4096]
    float* out = (float*)d_out;
    float* ws  = (float*)d_ws;

    float*  norms = ws + OFF_NORMS;
    float*  et    = ws + OFF_ET;
    float2* part  = (float2*)(ws + OFF_PART);
    int*    idx   = (int*)(ws + OFF_IDX);
    float*  dpart = ws + OFF_DP;

    k_norms<<<NEMB / 256, 256, 0, stream>>>(e, norms);
    k_transpose<<<dim3(NEMB / 32, KDIM / 32), dim3(32, 8), 0, stream>>>(e, et);
    k_gemm_argmin<<<dim3(NROWS / TM, NEMB / TN), 256, 0, stream>>>(x, e, norms, part);
    k_reduce<<<NROWS / 256, 256, 0, stream>>>(part, idx, out);
    k_gather<<<NROWS / 16, 256, 0, stream>>>(x, et, idx, out, dpart);
    k_diff<<<1, 256, 0, stream>>>(dpart, out);
}

// Round 2
// 850.934 us; speedup vs baseline: 3.2386x; 3.2386x over previous
//
#include <hip/hip_runtime.h>
#include <float.h>

#define NROWS 32768   // B*S = 8*4096
#define KDIM  512
#define NEMB  4096

#define TN 128
#define NCB (NEMB / TN)  // 32 code blocks

// ---- ws layout (float units) ----
#define OFF_NORMS 0u
#define OFF_ET    4096u
#define OFF_PART  (OFF_ET + 2097152u)         // float2: NROWS*NCB
#define OFF_IDX   (OFF_PART + 2097152u)
#define OFF_DP    (OFF_IDX + 32768u)
#define OFF_XHI   (OFF_DP + 2048u)            // shorts: NROWS*KDIM
#define OFF_XLO   (OFF_XHI + 8388608u)
#define OFF_EHI   (OFF_XLO + 8388608u)        // shorts: NEMB*KDIM
#define OFF_ELO   (OFF_EHI + 1048576u)
#define WS_FAST_FLOATS (OFF_ELO + 1048576u)   // ~92.4 MB
#define WS_SLOW_FLOATS (OFF_XHI)              // ~16.9 MB (round-1 path)

// ---- out layout (float units) ----
#define OUT_Q    0u
#define OUT_DIFF 16777216u
#define OUT_IDX  16777217u

typedef __attribute__((ext_vector_type(8))) short bf16x8;
typedef __attribute__((ext_vector_type(4))) float f32x4;

static __device__ inline unsigned short f2bf(float f) {
    unsigned u = __float_as_uint(f);
    unsigned r = (u + 0x7FFFu + ((u >> 16) & 1u)) >> 16;   // RNE
    return (unsigned short)r;
}
static __device__ inline float bf2f(unsigned short b) {
    return __uint_as_float(((unsigned)b) << 16);
}

// ---------------- kernel 1: code norms ||e_j||^2 (fp32, from original e) ----------------
__global__ __launch_bounds__(256) void k_norms(const float* __restrict__ e,
                                               float* __restrict__ norms) {
    int j = blockIdx.x * 256 + threadIdx.x;
    float s = 0.f;
    for (int k = 0; k < KDIM; ++k) {
        float v = e[(size_t)k * NEMB + j];
        s += v * v;
    }
    norms[j] = s;
}

// ---------------- kernel 2: transpose + hi/lo split of embed ----------------
// e [512][4096] -> et fp32 [4096][512], ethi/etlo bf16 [4096][512]
__global__ void k_split_et(const float* __restrict__ e, float* __restrict__ et,
                           unsigned short* __restrict__ ehi, unsigned short* __restrict__ elo) {
    __shared__ float t[32][33];
    int jb = blockIdx.x * 32;   // code dim
    int kb = blockIdx.y * 32;   // feature dim
    int tx = threadIdx.x;       // 32
    int ty = threadIdx.y;       // 8
    for (int i = ty; i < 32; i += 8)
        t[i][tx] = e[(size_t)(kb + i) * NEMB + jb + tx];
    __syncthreads();
    for (int i = ty; i < 32; i += 8) {
        float v = t[tx][i];
        size_t o = (size_t)(jb + i) * KDIM + kb + tx;
        et[o] = v;
        unsigned short h = f2bf(v);
        ehi[o] = h;
        elo[o] = f2bf(v - bf2f(h));
    }
}

// ---------------- kernel 3: hi/lo split of x ----------------
__global__ __launch_bounds__(256) void k_split_x(const float* __restrict__ x,
                                                 unsigned short* __restrict__ xhi,
                                                 unsigned short* __restrict__ xlo) {
    size_t i = ((size_t)blockIdx.x * 256 + threadIdx.x) * 4;
    float4 v = *(const float4*)(x + i);
    ushort4 h, l;
    h.x = f2bf(v.x); l.x = f2bf(v.x - bf2f(h.x));
    h.y = f2bf(v.y); l.y = f2bf(v.y - bf2f(h.y));
    h.z = f2bf(v.z); l.z = f2bf(v.z - bf2f(h.z));
    h.w = f2bf(v.w); l.w = f2bf(v.w - bf2f(h.w));
    *(ushort4*)(xhi + i) = h;
    *(ushort4*)(xlo + i) = l;
}

// ---------------- kernel 4: split-bf16 MFMA GEMM + per-code-block argmin ----------------
// grid (NROWS/128, NEMB/128), 256 threads (4 waves, 2x2), 128x128 tile, BK=32.
// 4 segments: (xh,eh) (xh,el) (xl,eh) (xl,el) accumulate into one fp32 acc.
__global__ __launch_bounds__(256) void k_mfma_argmin(
        const unsigned short* __restrict__ xhi, const unsigned short* __restrict__ xlo,
        const unsigned short* __restrict__ ehi, const unsigned short* __restrict__ elo,
        const float* __restrict__ norms, float2* __restrict__ part)
{
    __shared__ short As[2][128 * 32];   // [row][k] bf16, 8 KB each
    __shared__ short Bs[2][128 * 32];   // [col][k] bf16
    __shared__ float2 red[128][2];

    const int tid = threadIdx.x;
    const int wv = tid >> 6, ln = tid & 63;
    const int lr = ln & 15, hg = ln >> 4;
    const int wr = wv >> 1, wc = wv & 1;
    const int row0 = blockIdx.x * 128, col0 = blockIdx.y * 128;

    f32x4 acc[4][4];
#pragma unroll
    for (int m = 0; m < 4; ++m)
#pragma unroll
        for (int n = 0; n < 4; ++n) acc[m][n] = (f32x4){0.f, 0.f, 0.f, 0.f};

    // stage one 128x32 A-tile + B-tile for step = seg*16 + kk
#define STAGE(buf, step)                                                            \
    do {                                                                            \
        int seg_ = (step) >> 4;                                                     \
        int k0_ = ((step) & 15) * 32;                                               \
        const unsigned short* Asrc_ = (seg_ < 2) ? xhi : xlo;                       \
        const unsigned short* Bsrc_ = (seg_ & 1) ? elo : ehi;                       \
        _Pragma("unroll")                                                           \
        for (int i_ = 0; i_ < 2; ++i_) {                                            \
            int chunk_ = (i_ * 4 + wv) * 64 + ln;   /* 0..511, lane-ordered */      \
            int r_ = chunk_ >> 2, c8_ = chunk_ & 3;                                 \
            __builtin_amdgcn_global_load_lds(                                       \
                (const __attribute__((address_space(1))) void*)                     \
                    (Asrc_ + (size_t)(row0 + r_) * KDIM + k0_ + c8_ * 8),           \
                (__attribute__((address_space(3))) void*)&As[buf][(i_ * 4 + wv) * 512], \
                16, 0, 0);                                                          \
            __builtin_amdgcn_global_load_lds(                                       \
                (const __attribute__((address_space(1))) void*)                     \
                    (Bsrc_ + (size_t)(col0 + r_) * KDIM + k0_ + c8_ * 8),           \
                (__attribute__((address_space(3))) void*)&Bs[buf][(i_ * 4 + wv) * 512], \
                16, 0, 0);                                                          \
        }                                                                           \
    } while (0)

    STAGE(0, 0);
    __syncthreads();
    int cur = 0;
    for (int step = 0; step < 64; ++step) {
        if (step < 63) STAGE(cur ^ 1, step + 1);
        bf16x8 a[4], b[4];
#pragma unroll
        for (int m = 0; m < 4; ++m)
            a[m] = *(const bf16x8*)&As[cur][(wr * 64 + m * 16 + lr) * 32 + hg * 8];
#pragma unroll
        for (int n = 0; n < 4; ++n)
            b[n] = *(const bf16x8*)&Bs[cur][(wc * 64 + n * 16 + lr) * 32 + hg * 8];
#pragma unroll
        for (int m = 0; m < 4; ++m)
#pragma unroll
            for (int n = 0; n < 4; ++n)
                acc[m][n] = __builtin_amdgcn_mfma_f32_16x16x32_bf16(a[m], b[n], acc[m][n], 0, 0, 0);
        __syncthreads();
        cur ^= 1;
    }
#undef STAGE

    // epilogue: score = norms[col] - 2*dot ; argmin with first-index tie-break
    float nrm[4];
#pragma unroll
    for (int n = 0; n < 4; ++n) nrm[n] = norms[col0 + wc * 64 + n * 16 + lr];

#pragma unroll
    for (int m = 0; m < 4; ++m)
#pragma unroll
        for (int r = 0; r < 4; ++r) {
            float bs = FLT_MAX;
            int bc = 0x7FFFFFFF;
#pragma unroll
            for (int n = 0; n < 4; ++n) {
                float s = nrm[n] - 2.f * acc[m][n][r];
                int c = wc * 64 + n * 16 + lr;
                if (s < bs || (s == bs && c < bc)) { bs = s; bc = c; }
            }
#pragma unroll
            for (int off = 1; off < 16; off <<= 1) {
                float os = __shfl_xor(bs, off, 64);
                int oc = __shfl_xor(bc, off, 64);
                if (os < bs || (os == bs && oc < bc)) { bs = os; bc = oc; }
            }
            if (lr == 0)
                red[wr * 64 + m * 16 + hg * 4 + r][wc] = make_float2(bs, __int_as_float(bc));
        }
    __syncthreads();
    if (tid < 128) {
        float2 p0 = red[tid][0], p1 = red[tid][1];
        float bs = p0.x;
        int bc = __float_as_int(p0.y);
        if (p1.x < bs || (p1.x == bs && __float_as_int(p1.y) < bc)) {
            bs = p1.x; bc = __float_as_int(p1.y);
        }
        part[(size_t)(row0 + tid) * NCB + blockIdx.y] =
            make_float2(bs, __int_as_float(col0 + bc));
    }
}

// ---------------- fallback fp32 GEMM-argmin (round-1, ws-lean) ----------------
#define TMF 128
#define TKF 16
__global__ __launch_bounds__(256) void k_gemm_argmin(
        const float* __restrict__ x, const float* __restrict__ e,
        const float* __restrict__ norms, float2* __restrict__ part)
{
    __shared__ float xs[TKF][132];
    __shared__ float es[TKF][TN];
    __shared__ float2 red[TMF][16];

    const int row0 = blockIdx.x * TMF, col0 = blockIdx.y * TN;
    const int tid = threadIdx.x;
    const int ty = tid >> 4, tx = tid & 15;

    float acc[8][8];
#pragma unroll
    for (int i = 0; i < 8; ++i)
#pragma unroll
        for (int j = 0; j < 8; ++j) acc[i][j] = 0.f;

    for (int k0 = 0; k0 < KDIM; k0 += TKF) {
        __syncthreads();
#pragma unroll
        for (int s = 0; s < 2; ++s) {
            int slot = tid + s * 256;
            int r = slot >> 2, c4 = slot & 3;
            float4 v = *(const float4*)(x + (size_t)(row0 + r) * KDIM + k0 + c4 * 4);
            xs[c4 * 4 + 0][r] = v.x; xs[c4 * 4 + 1][r] = v.y;
            xs[c4 * 4 + 2][r] = v.z; xs[c4 * 4 + 3][r] = v.w;
        }
#pragma unroll
        for (int s = 0; s < 2; ++s) {
            int slot = tid + s * 256;
            int k = slot >> 5, c4 = slot & 31;
            *(float4*)(&es[k][c4 * 4]) =
                *(const float4*)(e + (size_t)(k0 + k) * NEMB + col0 + c4 * 4);
        }
        __syncthreads();
#pragma unroll
        for (int k = 0; k < TKF; ++k) {
            float xv[8], ev[8];
            *(float4*)&xv[0] = *(const float4*)&xs[k][ty * 8];
            *(float4*)&xv[4] = *(const float4*)&xs[k][ty * 8 + 4];
            *(float4*)&ev[0] = *(const float4*)&es[k][tx * 8];
            *(float4*)&ev[4] = *(const float4*)&es[k][tx * 8 + 4];
#pragma unroll
            for (int i = 0; i < 8; ++i)
#pragma unroll
                for (int j = 0; j < 8; ++j) acc[i][j] += xv[i] * ev[j];
        }
    }
    float nrm[8];
#pragma unroll
    for (int j = 0; j < 8; ++j) nrm[j] = norms[col0 + tx * 8 + j];
#pragma unroll
    for (int i = 0; i < 8; ++i) {
        float best = FLT_MAX; int bj = 0;
#pragma unroll
        for (int j = 0; j < 8; ++j) {
            float sc = nrm[j] - 2.f * acc[i][j];
            if (sc < best) { best = sc; bj = tx * 8 + j; }
        }
        red[ty * 8 + i][tx] = make_float2(best, __int_as_float(bj));
    }
    __syncthreads();
    if (tid < TMF) {
        float best = FLT_MAX; int bj = 0;
        for (int t = 0; t < 16; ++t) {
            float2 p = red[tid][t];
            if (p.x < best) { best = p.x; bj = __float_as_int(p.y); }
        }
        part[(size_t)(row0 + tid) * NCB + blockIdx.y] =
            make_float2(best, __int_as_float(col0 + bj));
    }
}

// fallback transpose (fp32 et only)
__global__ void k_transpose(const float* __restrict__ e, float* __restrict__ et) {
    __shared__ float t[32][33];
    int jb = blockIdx.x * 32, kb = blockIdx.y * 32;
    int tx = threadIdx.x, ty = threadIdx.y;
    for (int i = ty; i < 32; i += 8)
        t[i][tx] = e[(size_t)(kb + i) * NEMB + jb + tx];
    __syncthreads();
    for (int i = ty; i < 32; i += 8)
        et[(size_t)(jb + i) * KDIM + kb + tx] = t[tx][i];
}

// ---------------- kernel 5: reduce partial argmins ----------------
__global__ __launch_bounds__(256) void k_reduce(const float2* __restrict__ part,
                                                int* __restrict__ idx_out,
                                                float* __restrict__ out) {
    int row = blockIdx.x * 256 + threadIdx.x;
    float best = FLT_MAX;
    int bj = 0;
    for (int cbi = 0; cbi < NCB; ++cbi) {   // ascending = ascending code index
        float2 p = part[(size_t)row * NCB + cbi];
        if (p.x < best) { best = p.x; bj = __float_as_int(p.y); }
    }
    idx_out[row] = bj;
    out[OUT_IDX + row] = (float)bj;
}

// ---------------- kernel 6: gather quantize + diff partials ----------------
__global__ __launch_bounds__(256) void k_gather(const float* __restrict__ x,
                                                const float* __restrict__ et,
                                                const int* __restrict__ idx,
                                                float* __restrict__ out,
                                                float* __restrict__ dpart) {
    const int b = blockIdx.x;
    const int tid = threadIdx.x;
    const int row0 = b * 16;
    float s = 0.f;
    for (int i = tid; i < 16 * KDIM; i += 256) {
        int r = i >> 9;
        int k = i & (KDIM - 1);
        int row = row0 + r;
        float q = et[(size_t)idx[row] * KDIM + k];
        float xv = x[(size_t)row * KDIM + k];
        float d = q - xv;
        s += d * d;
        out[OUT_Q + (size_t)row * KDIM + k] = q;
    }
#pragma unroll
    for (int off = 32; off >= 1; off >>= 1) s += __shfl_down(s, off, 64);
    __shared__ float ws_[4];
    int lane = tid & 63, wvi = tid >> 6;
    if (lane == 0) ws_[wvi] = s;
    __syncthreads();
    if (tid == 0) dpart[b] = ws_[0] + ws_[1] + ws_[2] + ws_[3];
}

// ---------------- kernel 7: final diff ----------------
__global__ __launch_bounds__(256) void k_diff(const float* __restrict__ dpart,
                                              float* __restrict__ out) {
    int tid = threadIdx.x;
    float s = 0.f;
    for (int i = tid; i < 2048; i += 256) s += dpart[i];
#pragma unroll
    for (int off = 32; off >= 1; off >>= 1) s += __shfl_down(s, off, 64);
    __shared__ float ws_[4];
    int lane = tid & 63, wvi = tid >> 6;
    if (lane == 0) ws_[wvi] = s;
    __syncthreads();
    if (tid == 0) out[OUT_DIFF] = (ws_[0] + ws_[1] + ws_[2] + ws_[3]) / 16777216.f;
}

extern "C" void kernel_launch(void* const* d_in, const int* in_sizes, int n_in,
                              void* d_out, int out_size, void* d_ws, size_t ws_size,
                              hipStream_t stream) {
    const float* x = (const float*)d_in[0];   // [8,4096,512]
    const float* e = (const float*)d_in[1];   // [512,4096]
    float* out = (float*)d_out;
    float* ws = (float*)d_ws;

    float*  norms = ws + OFF_NORMS;
    float*  et    = ws + OFF_ET;
    float2* part  = (float2*)(ws + OFF_PART);
    int*    idx   = (int*)(ws + OFF_IDX);
    float*  dpart = ws + OFF_DP;

    k_norms<<<NEMB / 256, 256, 0, stream>>>(e, norms);

    if (ws_size >= (size_t)WS_FAST_FLOATS * 4) {
        unsigned short* xhi = (unsigned short*)(ws + OFF_XHI);
        unsigned short* xlo = (unsigned short*)(ws + OFF_XLO);
        unsigned short* ehi = (unsigned short*)(ws + OFF_EHI);
        unsigned short* elo = (unsigned short*)(ws + OFF_ELO);
        k_split_et<<<dim3(NEMB / 32, KDIM / 32), dim3(32, 8), 0, stream>>>(e, et, ehi, elo);
        k_split_x<<<(NROWS * KDIM) / (256 * 4), 256, 0, stream>>>(x, xhi, xlo);
        k_mfma_argmin<<<dim3(NROWS / 128, NEMB / 128), 256, 0, stream>>>(
            xhi, xlo, ehi, elo, norms, part);
    } else {
        k_transpose<<<dim3(NEMB / 32, KDIM / 32), dim3(32, 8), 0, stream>>>(e, et);
        k_gemm_argmin<<<dim3(NROWS / TMF, NEMB / TN), 256, 0, stream>>>(x, e, norms, part);
    }

    k_reduce<<<NROWS / 256, 256, 0, stream>>>(part, idx, out);
    k_gather<<<NROWS / 16, 256, 0, stream>>>(x, et, idx, out, dpart);
    k_diff<<<1, 256, 0, stream>>>(dpart, out);
}

// Round 3
// 767.864 us; speedup vs baseline: 3.5890x; 1.1082x over previous
//
#include <hip/hip_runtime.h>
#include <float.h>

#define NROWS 32768   // B*S = 8*4096
#define KDIM  512
#define NEMB  4096

#define TN 128
#define NCB (NEMB / TN)  // 32 code blocks

// ---- ws layout (float units) ----
#define OFF_NORMS 0u
#define OFF_ET    4096u
#define OFF_PART  (OFF_ET + 2097152u)         // float2: NROWS*NCB
#define OFF_IDX   (OFF_PART + 2097152u)
#define OFF_DP    (OFF_IDX + 32768u)
#define OFF_XHI   (OFF_DP + 2048u)            // shorts: NROWS*KDIM
#define OFF_XLO   (OFF_XHI + 8388608u)
#define OFF_EHI   (OFF_XLO + 8388608u)        // shorts: NEMB*KDIM
#define OFF_ELO   (OFF_EHI + 1048576u)
#define WS_FAST_FLOATS (OFF_ELO + 1048576u)   // ~92.4 MB
#define WS_SLOW_FLOATS (OFF_XHI)              // ~16.9 MB (round-1 path)

// ---- out layout (float units) ----
#define OUT_Q    0u
#define OUT_DIFF 16777216u
#define OUT_IDX  16777217u

typedef __attribute__((ext_vector_type(8))) short bf16x8;
typedef __attribute__((ext_vector_type(4))) float f32x4;

static __device__ inline unsigned short f2bf(float f) {
    unsigned u = __float_as_uint(f);
    unsigned r = (u + 0x7FFFu + ((u >> 16) & 1u)) >> 16;   // RNE
    return (unsigned short)r;
}
static __device__ inline float bf2f(unsigned short b) {
    return __uint_as_float(((unsigned)b) << 16);
}

// ---------------- kernel 1: code norms ||e_j||^2 (fp32, from original e) ----------------
__global__ __launch_bounds__(256) void k_norms(const float* __restrict__ e,
                                               float* __restrict__ norms) {
    int j = blockIdx.x * 256 + threadIdx.x;
    float s = 0.f;
    for (int k = 0; k < KDIM; ++k) {
        float v = e[(size_t)k * NEMB + j];
        s += v * v;
    }
    norms[j] = s;
}

// ---------------- kernel 2: transpose + hi/lo split of embed ----------------
__global__ void k_split_et(const float* __restrict__ e, float* __restrict__ et,
                           unsigned short* __restrict__ ehi, unsigned short* __restrict__ elo) {
    __shared__ float t[32][33];
    int jb = blockIdx.x * 32;   // code dim
    int kb = blockIdx.y * 32;   // feature dim
    int tx = threadIdx.x;       // 32
    int ty = threadIdx.y;       // 8
    for (int i = ty; i < 32; i += 8)
        t[i][tx] = e[(size_t)(kb + i) * NEMB + jb + tx];
    __syncthreads();
    for (int i = ty; i < 32; i += 8) {
        float v = t[tx][i];
        size_t o = (size_t)(jb + i) * KDIM + kb + tx;
        et[o] = v;
        unsigned short h = f2bf(v);
        ehi[o] = h;
        elo[o] = f2bf(v - bf2f(h));
    }
}

// ---------------- kernel 3: hi/lo split of x ----------------
__global__ __launch_bounds__(256) void k_split_x(const float* __restrict__ x,
                                                 unsigned short* __restrict__ xhi,
                                                 unsigned short* __restrict__ xlo) {
    size_t i = ((size_t)blockIdx.x * 256 + threadIdx.x) * 4;
    float4 v = *(const float4*)(x + i);
    ushort4 h, l;
    h.x = f2bf(v.x); l.x = f2bf(v.x - bf2f(h.x));
    h.y = f2bf(v.y); l.y = f2bf(v.y - bf2f(h.y));
    h.z = f2bf(v.z); l.z = f2bf(v.z - bf2f(h.z));
    h.w = f2bf(v.w); l.w = f2bf(v.w - bf2f(h.w));
    *(ushort4*)(xhi + i) = h;
    *(ushort4*)(xlo + i) = l;
}

// ---------------- kernel 4: split-bf16 MFMA GEMM + per-code-block argmin ----------------
// 1D grid 8192 (XCD-chunked supertiles), 256 threads (4 waves, 2x2), 128x128 tile, BK=32.
// 4 segments: (xh,eh) (xh,el) (xl,eh) (xl,el) accumulate into one fp32 acc.
// LDS tiles XOR-swizzled at 16B-chunk granularity: chunk' = chunk ^ ((row>>1)&3).
// gload_lds writes linearly, so the SOURCE address carries the inverse (== same) swizzle;
// ds_read applies it again -> identity on data, conflict-free banks (2 lanes/bank).
__global__ __launch_bounds__(256) void k_mfma_argmin(
        const unsigned short* __restrict__ xhi, const unsigned short* __restrict__ xlo,
        const unsigned short* __restrict__ ehi, const unsigned short* __restrict__ elo,
        const float* __restrict__ norms, float2* __restrict__ part)
{
    __shared__ short As[2][128 * 32];   // 8 KB each buffer
    __shared__ short Bs[2][128 * 32];
    __shared__ float2 red[128][2];

    const int tid = threadIdx.x;
    const int wv = tid >> 6, ln = tid & 63;
    const int lr = ln & 15, hg = ln >> 4;
    const int wr = wv >> 1, wc = wv & 1;

    // XCD-aware supertile decode: 8 XCDs x (4 rb-bands x [8 rb x 4 cb] supertiles, cb-major)
    const int orig = blockIdx.x;            // 0..8191
    const int xcd  = orig & 7;
    const int local = orig >> 3;            // 0..1023
    const int srow = local & 7;
    const int scol = (local >> 3) & 3;
    const int sblk = local >> 5;            // 0..31
    const int rb = xcd * 32 + (sblk >> 3) * 8 + srow;   // 0..255
    const int cb = (sblk & 7) * 4 + scol;               // 0..31
    const int row0 = rb * 128, col0 = cb * 128;

    // per-lane staging offsets (hoisted): slot s covers (r = s>>2, chunk = s&3),
    // source chunk swizzled: cg = chunk ^ ((r>>1)&3)
    size_t aoff[2], boff[2];
#pragma unroll
    for (int i = 0; i < 2; ++i) {
        int slot = (i * 4 + wv) * 64 + ln;
        int r = slot >> 2;
        int cg = (slot & 3) ^ ((r >> 1) & 3);
        aoff[i] = (size_t)(row0 + r) * KDIM + cg * 8;
        boff[i] = (size_t)(col0 + r) * KDIM + cg * 8;
    }

    f32x4 acc[4][4];
#pragma unroll
    for (int m = 0; m < 4; ++m)
#pragma unroll
        for (int n = 0; n < 4; ++n) acc[m][n] = (f32x4){0.f, 0.f, 0.f, 0.f};

#define STAGE(buf, step)                                                            \
    do {                                                                            \
        int seg_ = (step) >> 4;                                                     \
        int k0_ = ((step) & 15) * 32;                                               \
        const unsigned short* Asrc_ = (seg_ < 2) ? xhi : xlo;                       \
        const unsigned short* Bsrc_ = (seg_ & 1) ? elo : ehi;                       \
        _Pragma("unroll")                                                           \
        for (int i_ = 0; i_ < 2; ++i_) {                                            \
            __builtin_amdgcn_global_load_lds(                                       \
                (const __attribute__((address_space(1))) void*)(Asrc_ + aoff[i_] + k0_), \
                (__attribute__((address_space(3))) void*)&As[buf][(i_ * 4 + wv) * 512], \
                16, 0, 0);                                                          \
            __builtin_amdgcn_global_load_lds(                                       \
                (const __attribute__((address_space(1))) void*)(Bsrc_ + boff[i_] + k0_), \
                (__attribute__((address_space(3))) void*)&Bs[buf][(i_ * 4 + wv) * 512], \
                16, 0, 0);                                                          \
        }                                                                           \
    } while (0)

    STAGE(0, 0);
    __syncthreads();
    int cur = 0;
    // swizzled read chunk per lane: hg ^ ((row>>1)&3), row bits 1-2 come from lr only
    const int swz = (hg ^ ((lr >> 1) & 3)) * 8;
    for (int step = 0; step < 64; ++step) {
        if (step < 63) STAGE(cur ^ 1, step + 1);
        bf16x8 a[4], b[4];
#pragma unroll
        for (int m = 0; m < 4; ++m)
            a[m] = *(const bf16x8*)&As[cur][(wr * 64 + m * 16 + lr) * 32 + swz];
#pragma unroll
        for (int n = 0; n < 4; ++n)
            b[n] = *(const bf16x8*)&Bs[cur][(wc * 64 + n * 16 + lr) * 32 + swz];
#pragma unroll
        for (int m = 0; m < 4; ++m)
#pragma unroll
            for (int n = 0; n < 4; ++n)
                acc[m][n] = __builtin_amdgcn_mfma_f32_16x16x32_bf16(a[m], b[n], acc[m][n], 0, 0, 0);
        __syncthreads();
        cur ^= 1;
    }
#undef STAGE

    // epilogue: score = norms[col] - 2*dot ; argmin with first-index tie-break
    float nrm[4];
#pragma unroll
    for (int n = 0; n < 4; ++n) nrm[n] = norms[col0 + wc * 64 + n * 16 + lr];

#pragma unroll
    for (int m = 0; m < 4; ++m)
#pragma unroll
        for (int r = 0; r < 4; ++r) {
            float bs = FLT_MAX;
            int bc = 0x7FFFFFFF;
#pragma unroll
            for (int n = 0; n < 4; ++n) {
                float s = nrm[n] - 2.f * acc[m][n][r];
                int c = wc * 64 + n * 16 + lr;
                if (s < bs || (s == bs && c < bc)) { bs = s; bc = c; }
            }
#pragma unroll
            for (int off = 1; off < 16; off <<= 1) {
                float os = __shfl_xor(bs, off, 64);
                int oc = __shfl_xor(bc, off, 64);
                if (os < bs || (os == bs && oc < bc)) { bs = os; bc = oc; }
            }
            if (lr == 0)
                red[wr * 64 + m * 16 + hg * 4 + r][wc] = make_float2(bs, __int_as_float(bc));
        }
    __syncthreads();
    if (tid < 128) {
        float2 p0 = red[tid][0], p1 = red[tid][1];
        float bs = p0.x;
        int bc = __float_as_int(p0.y);
        if (p1.x < bs || (p1.x == bs && __float_as_int(p1.y) < bc)) {
            bs = p1.x; bc = __float_as_int(p1.y);
        }
        part[(size_t)(row0 + tid) * NCB + cb] =
            make_float2(bs, __int_as_float(col0 + bc));
    }
}

// ---------------- fallback fp32 GEMM-argmin (round-1, ws-lean) ----------------
#define TMF 128
#define TKF 16
__global__ __launch_bounds__(256) void k_gemm_argmin(
        const float* __restrict__ x, const float* __restrict__ e,
        const float* __restrict__ norms, float2* __restrict__ part)
{
    __shared__ float xs[TKF][132];
    __shared__ float es[TKF][TN];
    __shared__ float2 red[TMF][16];

    const int row0 = blockIdx.x * TMF, col0 = blockIdx.y * TN;
    const int tid = threadIdx.x;
    const int ty = tid >> 4, tx = tid & 15;

    float acc[8][8];
#pragma unroll
    for (int i = 0; i < 8; ++i)
#pragma unroll
        for (int j = 0; j < 8; ++j) acc[i][j] = 0.f;

    for (int k0 = 0; k0 < KDIM; k0 += TKF) {
        __syncthreads();
#pragma unroll
        for (int s = 0; s < 2; ++s) {
            int slot = tid + s * 256;
            int r = slot >> 2, c4 = slot & 3;
            float4 v = *(const float4*)(x + (size_t)(row0 + r) * KDIM + k0 + c4 * 4);
            xs[c4 * 4 + 0][r] = v.x; xs[c4 * 4 + 1][r] = v.y;
            xs[c4 * 4 + 2][r] = v.z; xs[c4 * 4 + 3][r] = v.w;
        }
#pragma unroll
        for (int s = 0; s < 2; ++s) {
            int slot = tid + s * 256;
            int k = slot >> 5, c4 = slot & 31;
            *(float4*)(&es[k][c4 * 4]) =
                *(const float4*)(e + (size_t)(k0 + k) * NEMB + col0 + c4 * 4);
        }
        __syncthreads();
#pragma unroll
        for (int k = 0; k < TKF; ++k) {
            float xv[8], ev[8];
            *(float4*)&xv[0] = *(const float4*)&xs[k][ty * 8];
            *(float4*)&xv[4] = *(const float4*)&xs[k][ty * 8 + 4];
            *(float4*)&ev[0] = *(const float4*)&es[k][tx * 8];
            *(float4*)&ev[4] = *(const float4*)&es[k][tx * 8 + 4];
#pragma unroll
            for (int i = 0; i < 8; ++i)
#pragma unroll
                for (int j = 0; j < 8; ++j) acc[i][j] += xv[i] * ev[j];
        }
    }
    float nrm[8];
#pragma unroll
    for (int j = 0; j < 8; ++j) nrm[j] = norms[col0 + tx * 8 + j];
#pragma unroll
    for (int i = 0; i < 8; ++i) {
        float best = FLT_MAX; int bj = 0;
#pragma unroll
        for (int j = 0; j < 8; ++j) {
            float sc = nrm[j] - 2.f * acc[i][j];
            if (sc < best) { best = sc; bj = tx * 8 + j; }
        }
        red[ty * 8 + i][tx] = make_float2(best, __int_as_float(bj));
    }
    __syncthreads();
    if (tid < TMF) {
        float best = FLT_MAX; int bj = 0;
        for (int t = 0; t < 16; ++t) {
            float2 p = red[tid][t];
            if (p.x < best) { best = p.x; bj = __float_as_int(p.y); }
        }
        part[(size_t)(row0 + tid) * NCB + blockIdx.y] =
            make_float2(best, __int_as_float(col0 + bj));
    }
}

// fallback transpose (fp32 et only)
__global__ void k_transpose(const float* __restrict__ e, float* __restrict__ et) {
    __shared__ float t[32][33];
    int jb = blockIdx.x * 32, kb = blockIdx.y * 32;
    int tx = threadIdx.x, ty = threadIdx.y;
    for (int i = ty; i < 32; i += 8)
        t[i][tx] = e[(size_t)(kb + i) * NEMB + jb + tx];
    __syncthreads();
    for (int i = ty; i < 32; i += 8)
        et[(size_t)(jb + i) * KDIM + kb + tx] = t[tx][i];
}

// ---------------- kernel 5: reduce partial argmins ----------------
__global__ __launch_bounds__(256) void k_reduce(const float2* __restrict__ part,
                                                int* __restrict__ idx_out,
                                                float* __restrict__ out) {
    int row = blockIdx.x * 256 + threadIdx.x;
    float best = FLT_MAX;
    int bj = 0;
    for (int cbi = 0; cbi < NCB; ++cbi) {   // ascending = ascending code index
        float2 p = part[(size_t)row * NCB + cbi];
        if (p.x < best) { best = p.x; bj = __float_as_int(p.y); }
    }
    idx_out[row] = bj;
    out[OUT_IDX + row] = (float)bj;
}

// ---------------- kernel 6: gather quantize + diff partials ----------------
__global__ __launch_bounds__(256) void k_gather(const float* __restrict__ x,
                                                const float* __restrict__ et,
                                                const int* __restrict__ idx,
                                                float* __restrict__ out,
                                                float* __restrict__ dpart) {
    const int b = blockIdx.x;
    const int tid = threadIdx.x;
    const int row0 = b * 16;
    float s = 0.f;
    for (int i = tid; i < 16 * KDIM; i += 256) {
        int r = i >> 9;
        int k = i & (KDIM - 1);
        int row = row0 + r;
        float q = et[(size_t)idx[row] * KDIM + k];
        float xv = x[(size_t)row * KDIM + k];
        float d = q - xv;
        s += d * d;
        out[OUT_Q + (size_t)row * KDIM + k] = q;
    }
#pragma unroll
    for (int off = 32; off >= 1; off >>= 1) s += __shfl_down(s, off, 64);
    __shared__ float ws_[4];
    int lane = tid & 63, wvi = tid >> 6;
    if (lane == 0) ws_[wvi] = s;
    __syncthreads();
    if (tid == 0) dpart[b] = ws_[0] + ws_[1] + ws_[2] + ws_[3];
}

// ---------------- kernel 7: final diff ----------------
__global__ __launch_bounds__(256) void k_diff(const float* __restrict__ dpart,
                                              float* __restrict__ out) {
    int tid = threadIdx.x;
    float s = 0.f;
    for (int i = tid; i < 2048; i += 256) s += dpart[i];
#pragma unroll
    for (int off = 32; off >= 1; off >>= 1) s += __shfl_down(s, off, 64);
    __shared__ float ws_[4];
    int lane = tid & 63, wvi = tid >> 6;
    if (lane == 0) ws_[wvi] = s;
    __syncthreads();
    if (tid == 0) out[OUT_DIFF] = (ws_[0] + ws_[1] + ws_[2] + ws_[3]) / 16777216.f;
}

extern "C" void kernel_launch(void* const* d_in, const int* in_sizes, int n_in,
                              void* d_out, int out_size, void* d_ws, size_t ws_size,
                              hipStream_t stream) {
    const float* x = (const float*)d_in[0];   // [8,4096,512]
    const float* e = (const float*)d_in[1];   // [512,4096]
    float* out = (float*)d_out;
    float* ws = (float*)d_ws;

    float*  norms = ws + OFF_NORMS;
    float*  et    = ws + OFF_ET;
    float2* part  = (float2*)(ws + OFF_PART);
    int*    idx   = (int*)(ws + OFF_IDX);
    float*  dpart = ws + OFF_DP;

    k_norms<<<NEMB / 256, 256, 0, stream>>>(e, norms);

    if (ws_size >= (size_t)WS_FAST_FLOATS * 4) {
        unsigned short* xhi = (unsigned short*)(ws + OFF_XHI);
        unsigned short* xlo = (unsigned short*)(ws + OFF_XLO);
        unsigned short* ehi = (unsigned short*)(ws + OFF_EHI);
        unsigned short* elo = (unsigned short*)(ws + OFF_ELO);
        k_split_et<<<dim3(NEMB / 32, KDIM / 32), dim3(32, 8), 0, stream>>>(e, et, ehi, elo);
        k_split_x<<<(NROWS * KDIM) / (256 * 4), 256, 0, stream>>>(x, xhi, xlo);
        k_mfma_argmin<<<8192, 256, 0, stream>>>(xhi, xlo, ehi, elo, norms, part);
    } else {
        k_transpose<<<dim3(NEMB / 32, KDIM / 32), dim3(32, 8), 0, stream>>>(e, et);
        k_gemm_argmin<<<dim3(NROWS / TMF, NEMB / TN), 256, 0, stream>>>(x, e, norms, part);
    }

    k_reduce<<<NROWS / 256, 256, 0, stream>>>(part, idx, out);
    k_gather<<<NROWS / 16, 256, 0, stream>>>(x, et, idx, out, dpart);
    k_diff<<<1, 256, 0, stream>>>(dpart, out);
}